// Round 1
// baseline (7419.086 us; speedup 1.0000x reference)
//
#include <hip/hip_runtime.h>
#include <hip/hip_bf16.h>

// Problem constants (B=4, C=256, T=4096, Cq=32)
#define BB 4
#define CC 256
#define TT 4096
#define CQ 32

// ---------------------------------------------------------------------------
// Projection kernel: out[b][t][o] = sum_c W[o][c] * x[b][c][t] + bias[o]
// Grid: (TT/64, odim/32, BB), block 256.
// Weights tile (32 o-rows x 256 c) staged in LDS; x read directly from global
// with lanes varying t (coalesced), reused across the 4 o-subgroups via the
// coalescer (same-address broadcast within the wave).
// ---------------------------------------------------------------------------
__global__ __launch_bounds__(256) void proj_kernel(
    const float* __restrict__ x, const float* __restrict__ W,
    const float* __restrict__ bias, float* __restrict__ out, int odim)
{
    __shared__ float ws[32 * 256];   // [o_local][c], 32 KB

    const int tid = threadIdx.x;
    const int t0  = blockIdx.x * 64;
    const int o0  = blockIdx.y * 32;
    const int b   = blockIdx.z;

    // stage weight tile: 8192 floats = 2048 float4, 8 iters
    #pragma unroll
    for (int it = 0; it < 8; ++it) {
        int idx = it * 256 + tid;          // 0..2047
        int j   = idx >> 6;                // 0..31
        int c4  = idx & 63;                // 0..63
        float4 v = *(const float4*)(W + (size_t)(o0 + j) * CC + c4 * 4);
        *(float4*)(ws + j * 256 + c4 * 4) = v;
    }
    __syncthreads();

    const int t    = tid & 63;
    const int osub = tid >> 6;             // 0..3, each handles 8 o's
    const float* xcol = x + (size_t)b * CC * TT + t0 + t;  // x[b][c][t0+t] = xcol[c*TT]

    float acc[8];
    #pragma unroll
    for (int jj = 0; jj < 8; ++jj) acc[jj] = bias[o0 + osub * 8 + jj];

    for (int c = 0; c < 256; c += 4) {
        float x0 = xcol[(size_t)(c + 0) * TT];
        float x1 = xcol[(size_t)(c + 1) * TT];
        float x2 = xcol[(size_t)(c + 2) * TT];
        float x3 = xcol[(size_t)(c + 3) * TT];
        #pragma unroll
        for (int jj = 0; jj < 8; ++jj) {
            const float4 w4 = *(const float4*)(ws + (osub * 8 + jj) * 256 + c);
            acc[jj] += w4.x * x0 + w4.y * x1 + w4.z * x2 + w4.w * x3;
        }
    }

    float* op = out + ((size_t)(b * TT + t0 + t)) * odim + o0 + osub * 8;
    #pragma unroll
    for (int jj = 0; jj < 8; ++jj) op[jj] = acc[jj];
}

// ---------------------------------------------------------------------------
// Flash attention kernel (fp32, online softmax).
// Q layout: [b][t][o] (o contiguous, 32), K layout: [b][s][o], V: [b][s][c].
// Grid: (TT/32, BB), block 256 (4 waves).
// Per block: 32 q-rows. s-loop in tiles of 64.
// Thread roles:
//   S-compute: s_col = tid&63, rg = tid>>6 -> rows rg*8..rg*8+7
//   PV:        r_pv  = tid>>3, cg = tid&7  -> cols cg*32..cg*32+31 (O[32] regs)
// ---------------------------------------------------------------------------
__global__ __launch_bounds__(256) void flash_kernel(
    const float* __restrict__ Q, const float* __restrict__ K,
    const float* __restrict__ V, const float* __restrict__ x,
    float* __restrict__ out)
{
    __shared__ float Qs[32 * 32];       // [r][o]
    __shared__ float Ks[64 * 36];       // [s][o], pad 36 (16B-aligned rows)
    __shared__ float Ss[32 * 66];       // [r][s], pad 66
    __shared__ float trans[64 * 33];    // epilogue transpose buffer
    __shared__ float Mrun[32], row_alpha[32], row_sum[32];

    const int tid = threadIdx.x;
    const int t0  = blockIdx.x * 32;
    const int b   = blockIdx.y;

    // load Q tile: 1024 floats = 256 float4
    {
        int r = tid >> 3, o4 = tid & 7;
        float4 v = *(const float4*)(Q + ((size_t)(b * TT) + t0 + r) * CQ + o4 * 4);
        *(float4*)(Qs + r * 32 + o4 * 4) = v;
    }
    if (tid < 32) Mrun[tid] = -3.0e38f;

    const int r_pv  = tid >> 3;
    const int cg    = tid & 7;
    const int s_col = tid & 63;
    const int rg    = tid >> 6;

    float O[32];
    #pragma unroll
    for (int j = 0; j < 32; ++j) O[j] = 0.f;
    float l = 0.f;

    const float* Vb = V + (size_t)b * TT * CC;
    const float* Kb = K + (size_t)b * TT * CQ;

    for (int st = 0; st < TT / 64; ++st) {
        const int s0 = st * 64;

        // load K tile: 2048 floats = 512 float4, 2 per thread
        #pragma unroll
        for (int it = 0; it < 2; ++it) {
            int idx = it * 256 + tid;      // 0..511
            int s = idx >> 3, o4 = idx & 7;
            float4 v = *(const float4*)(Kb + (size_t)(s0 + s) * CQ + o4 * 4);
            *(float4*)(Ks + s * 36 + o4 * 4) = v;
        }
        __syncthreads();

        // S = Q K^T  (each thread: column s_col, 8 rows)
        {
            float acc[8];
            #pragma unroll
            for (int j = 0; j < 8; ++j) acc[j] = 0.f;
            #pragma unroll 4
            for (int o = 0; o < 32; ++o) {
                float kv = Ks[s_col * 36 + o];
                #pragma unroll
                for (int j = 0; j < 8; ++j)
                    acc[j] += Qs[(rg * 8 + j) * 32 + o] * kv;
            }
            #pragma unroll
            for (int j = 0; j < 8; ++j) Ss[(rg * 8 + j) * 66 + s_col] = acc[j];
        }
        __syncthreads();

        // online softmax, one thread per row
        if (tid < 32) {
            float mold = Mrun[tid];
            float mx = mold;
            #pragma unroll 8
            for (int s = 0; s < 64; ++s) mx = fmaxf(mx, Ss[tid * 66 + s]);
            float al = __expf(mold - mx);
            float sum = 0.f;
            #pragma unroll 8
            for (int s = 0; s < 64; ++s) {
                float p = __expf(Ss[tid * 66 + s] - mx);
                Ss[tid * 66 + s] = p;
                sum += p;
            }
            Mrun[tid] = mx; row_alpha[tid] = al; row_sum[tid] = sum;
        }
        __syncthreads();

        // O = O*alpha + P @ V_tile
        {
            float al = row_alpha[r_pv];
            l = l * al + row_sum[r_pv];
            #pragma unroll
            for (int j = 0; j < 32; ++j) O[j] *= al;
            const float* vp = Vb + (size_t)s0 * CC + cg * 32;
            for (int s = 0; s < 64; ++s) {
                float p = Ss[r_pv * 66 + s];
                const float4* v4 = (const float4*)(vp + (size_t)s * CC);
                #pragma unroll
                for (int k = 0; k < 8; ++k) {
                    float4 vv = v4[k];
                    O[k * 4 + 0] += p * vv.x;
                    O[k * 4 + 1] += p * vv.y;
                    O[k * 4 + 2] += p * vv.z;
                    O[k * 4 + 3] += p * vv.w;
                }
            }
        }
        __syncthreads();
    }

    // epilogue: out[b][c][t0+r] = O/l + x, via LDS transpose for coalesced stores
    float inv_l = 1.f / l;
    #pragma unroll
    for (int j = 0; j < 32; ++j) O[j] *= inv_l;

    for (int cc = 0; cc < 4; ++cc) {
        __syncthreads();
        if ((cg >> 1) == cc) {
            int h = cg & 1;
            #pragma unroll
            for (int j = 0; j < 32; ++j)
                trans[(h * 32 + j) * 33 + r_pv] = O[j];
        }
        __syncthreads();
        int r2 = tid & 31;
        int cbase = tid >> 5;
        #pragma unroll
        for (int it = 0; it < 8; ++it) {
            int cp = cbase + it * 8;
            float val = trans[cp * 33 + r2];
            size_t addr = ((size_t)(b * CC + cc * 64 + cp)) * TT + t0 + r2;
            out[addr] = val + x[addr];
        }
    }
}

// ---------------------------------------------------------------------------
extern "C" void kernel_launch(void* const* d_in, const int* in_sizes, int n_in,
                              void* d_out, int out_size, void* d_ws, size_t ws_size,
                              hipStream_t stream) {
    const float* x  = (const float*)d_in[0];
    const float* Wq = (const float*)d_in[1];
    const float* bq = (const float*)d_in[2];
    const float* Wk = (const float*)d_in[3];
    const float* bk = (const float*)d_in[4];
    const float* Wv = (const float*)d_in[5];
    const float* bv = (const float*)d_in[6];
    float* out = (float*)d_out;

    // workspace: Q [B][T][CQ], K [B][T][CQ], V [B][T][C]  (20 MB total)
    float* Qw = (float*)d_ws;
    float* Kw = Qw + (size_t)BB * TT * CQ;
    float* Vw = Kw + (size_t)BB * TT * CQ;

    dim3 blk(256);
    proj_kernel<<<dim3(TT / 64, CQ / 32, BB), blk, 0, stream>>>(x, Wq, bq, Qw, CQ);
    proj_kernel<<<dim3(TT / 64, CQ / 32, BB), blk, 0, stream>>>(x, Wk, bk, Kw, CQ);
    proj_kernel<<<dim3(TT / 64, CC / 32, BB), blk, 0, stream>>>(x, Wv, bv, Vw, CC);
    flash_kernel<<<dim3(TT / 32, BB), blk, 0, stream>>>(Qw, Kw, Vw, x, out);
}

// Round 2
// 273.090 us; speedup vs baseline: 27.1672x; 27.1672x over previous
//
#include <hip/hip_runtime.h>
#include <hip/hip_bf16.h>

// Problem constants (B=4, C=256, T=4096, Cq=32)
#define BB 4
#define CC 256
#define TT 4096
#define CQ 32

typedef __bf16 bf16;
typedef __bf16 bf16x8 __attribute__((ext_vector_type(8)));
typedef float floatx4 __attribute__((ext_vector_type(4)));

// ---------------------------------------------------------------------------
// Projection: out = W @ x + b, fp32 compute, bf16 output.
// vmode=0: out[b][t][o]   (o contiguous; for Q and K, odim=32)
// vmode=1: out[b][o][t]   (t contiguous; for V, odim=256)
// Grid: (TT/64, odim/32, BB), block 256.
// ---------------------------------------------------------------------------
__global__ __launch_bounds__(256) void proj_kernel(
    const float* __restrict__ x, const float* __restrict__ W,
    const float* __restrict__ bias, bf16* __restrict__ out, int odim, int vmode)
{
    __shared__ float ws[32 * 256];   // [o_local][c]

    const int tid = threadIdx.x;
    const int t0  = blockIdx.x * 64;
    const int o0  = blockIdx.y * 32;
    const int b   = blockIdx.z;

    #pragma unroll
    for (int it = 0; it < 8; ++it) {
        int idx = it * 256 + tid;
        int j   = idx >> 6;
        int c4  = idx & 63;
        float4 v = *(const float4*)(W + (size_t)(o0 + j) * CC + c4 * 4);
        *(float4*)(ws + j * 256 + c4 * 4) = v;
    }
    __syncthreads();

    const int t    = tid & 63;
    const int osub = tid >> 6;
    const float* xcol = x + (size_t)b * CC * TT + t0 + t;

    float acc[8];
    #pragma unroll
    for (int jj = 0; jj < 8; ++jj) acc[jj] = bias[o0 + osub * 8 + jj];

    for (int c = 0; c < 256; c += 4) {
        float x0 = xcol[(size_t)(c + 0) * TT];
        float x1 = xcol[(size_t)(c + 1) * TT];
        float x2 = xcol[(size_t)(c + 2) * TT];
        float x3 = xcol[(size_t)(c + 3) * TT];
        #pragma unroll
        for (int jj = 0; jj < 8; ++jj) {
            const float4 w4 = *(const float4*)(ws + (osub * 8 + jj) * 256 + c);
            acc[jj] += w4.x * x0 + w4.y * x1 + w4.z * x2 + w4.w * x3;
        }
    }

    if (vmode == 0) {
        bf16x8 v;
        #pragma unroll
        for (int jj = 0; jj < 8; ++jj) v[jj] = (bf16)acc[jj];
        *(bf16x8*)(out + ((size_t)(b * TT + t0 + t)) * odim + o0 + osub * 8) = v;
    } else {
        #pragma unroll
        for (int jj = 0; jj < 8; ++jj)
            out[((size_t)(b * odim + o0 + osub * 8 + jj)) * TT + t0 + t] = (bf16)acc[jj];
    }
}

// ---------------------------------------------------------------------------
// Flash attention, bf16 MFMA. Br=32 q-rows/block, Bc=64 s-cols/tile.
// Grid (TT/32, BB), 256 threads = 4 waves.
// Q: [b][t][32] bf16, K: [b][s][32] bf16, V: [b][c][t] bf16.
// MFMA 16x16x32 layouts (verified, learn_hip m89/m120):
//   A[m=lane&15][k=quad*8+j], B[k=quad*8+j][n=lane&15],
//   C/D[row=quad*4+r][col=lane&15], quad=lane>>4.
// Per s-tile: S(32x64)=Q K^T (8 MFMAs, 2/wave), LDS softmax round-trip,
// PV: P(32x64)@V(64x256) (64 MFMAs, 16/wave; wave w owns c-cols 64w..64w+63).
// LDS strides padded (40/72/68) -> frag reads are <=2-way bank-aliased (free).
// ---------------------------------------------------------------------------
__global__ __launch_bounds__(256) void flash_kernel(
    const bf16* __restrict__ Q, const bf16* __restrict__ K,
    const bf16* __restrict__ V, const float* __restrict__ x,
    float* __restrict__ out)
{
    __shared__ bf16 Qs[32 * 40];      // [r][k]
    __shared__ bf16 Ks[64 * 40];      // [s][o]
    __shared__ bf16 Vs[256 * 72];     // [c][s]
    __shared__ bf16 Ps[32 * 72];      // [r][s]
    __shared__ float Sf[32 * 68];     // [r][s]
    __shared__ float Mrun[32], alphaS[32], Lrun[32];

    const int tid  = threadIdx.x;
    const int t0   = blockIdx.x * 32;
    const int b    = blockIdx.y;
    const int lane = tid & 63;
    const int w    = tid >> 6;
    const int l15  = lane & 15;
    const int quad = lane >> 4;

    // Q tile 32x32 -> Qs
    {
        int r = tid >> 3, k4 = (tid & 7) * 4;
        *(uint2*)(Qs + r * 40 + k4) =
            *(const uint2*)(Q + ((size_t)(b * TT) + t0 + r) * CQ + k4);
    }
    if (tid < 32) { Mrun[tid] = -1.0e30f; Lrun[tid] = 0.f; }

    floatx4 acc[2][4] = {};    // O accumulators [m][nt]

    const bf16* Kb = K + (size_t)b * TT * CQ;
    const bf16* Vb = V + (size_t)b * CC * TT;

    for (int st = 0; st < TT / 64; ++st) {
        const int s0 = st * 64;
        __syncthreads();   // protect Ks/Vs/Ps against prior-iter readers

        // stage K tile 64x32
        {
            int s = tid >> 2, k8 = (tid & 3) * 8;
            *(uint4*)(Ks + s * 40 + k8) =
                *(const uint4*)(Kb + (size_t)(s0 + s) * CQ + k8);
        }
        // stage V tile 256x64 as [c][s]
        #pragma unroll
        for (int it = 0; it < 8; ++it) {
            int idx = it * 256 + tid;
            int c = idx >> 3, sb = (idx & 7) * 8;
            *(uint4*)(Vs + c * 72 + sb) =
                *(const uint4*)(Vb + (size_t)c * TT + s0 + sb);
        }
        __syncthreads();

        // S = Q K^T: wave w -> cols 16w..16w+15, rows 0..31
        {
            bf16x8 bk = *(const bf16x8*)(Ks + (w * 16 + l15) * 40 + quad * 8);
            bf16x8 a0 = *(const bf16x8*)(Qs + l15 * 40 + quad * 8);
            bf16x8 a1 = *(const bf16x8*)(Qs + (16 + l15) * 40 + quad * 8);
            floatx4 sc0 = {}, sc1 = {};
            sc0 = __builtin_amdgcn_mfma_f32_16x16x32_bf16(a0, bk, sc0, 0, 0, 0);
            sc1 = __builtin_amdgcn_mfma_f32_16x16x32_bf16(a1, bk, sc1, 0, 0, 0);
            #pragma unroll
            for (int r = 0; r < 4; ++r) {
                Sf[(quad * 4 + r) * 68 + w * 16 + l15]        = sc0[r];
                Sf[(16 + quad * 4 + r) * 68 + w * 16 + l15]   = sc1[r];
            }
        }
        __syncthreads();

        // online softmax: row = tid>>3 (8 threads/row), cols (tid&7)*8..+8
        {
            int r = tid >> 3, c8 = tid & 7;
            float* sp = Sf + r * 68 + c8 * 8;
            float4 f0 = *(const float4*)(sp);
            float4 f1 = *(const float4*)(sp + 4);
            float mold = Mrun[r];
            float mx = fmaxf(fmaxf(fmaxf(f0.x, f0.y), fmaxf(f0.z, f0.w)),
                             fmaxf(fmaxf(f1.x, f1.y), fmaxf(f1.z, f1.w)));
            mx = fmaxf(mx, __shfl_xor(mx, 1));
            mx = fmaxf(mx, __shfl_xor(mx, 2));
            mx = fmaxf(mx, __shfl_xor(mx, 4));
            float m_new = fmaxf(mold, mx);
            float p[8];
            p[0] = __expf(f0.x - m_new); p[1] = __expf(f0.y - m_new);
            p[2] = __expf(f0.z - m_new); p[3] = __expf(f0.w - m_new);
            p[4] = __expf(f1.x - m_new); p[5] = __expf(f1.y - m_new);
            p[6] = __expf(f1.z - m_new); p[7] = __expf(f1.w - m_new);
            float sum = (p[0]+p[1]+p[2]+p[3]) + (p[4]+p[5]+p[6]+p[7]);
            sum += __shfl_xor(sum, 1);
            sum += __shfl_xor(sum, 2);
            sum += __shfl_xor(sum, 4);
            bf16x8 pv;
            #pragma unroll
            for (int j = 0; j < 8; ++j) pv[j] = (bf16)p[j];
            *(bf16x8*)(Ps + r * 72 + c8 * 8) = pv;
            if (c8 == 0) {
                alphaS[r] = __expf(mold - m_new);
                Mrun[r]   = m_new;
                Lrun[r]   = Lrun[r] * __expf(mold - m_new) + sum;
            }
        }
        __syncthreads();

        // O = O*alpha + P @ V_tile; wave w owns c-cols 64w..64w+63
        {
            float al[2][4];
            #pragma unroll
            for (int m = 0; m < 2; ++m)
                #pragma unroll
                for (int r = 0; r < 4; ++r)
                    al[m][r] = alphaS[m * 16 + quad * 4 + r];
            #pragma unroll
            for (int m = 0; m < 2; ++m)
                #pragma unroll
                for (int nt = 0; nt < 4; ++nt)
                    #pragma unroll
                    for (int r = 0; r < 4; ++r)
                        acc[m][nt][r] *= al[m][r];

            #pragma unroll
            for (int kt = 0; kt < 2; ++kt) {
                bf16x8 a0 = *(const bf16x8*)(Ps + l15 * 72 + kt * 32 + quad * 8);
                bf16x8 a1 = *(const bf16x8*)(Ps + (16 + l15) * 72 + kt * 32 + quad * 8);
                #pragma unroll
                for (int nt = 0; nt < 4; ++nt) {
                    bf16x8 bv = *(const bf16x8*)(Vs + (w * 64 + nt * 16 + l15) * 72 + kt * 32 + quad * 8);
                    acc[0][nt] = __builtin_amdgcn_mfma_f32_16x16x32_bf16(a0, bv, acc[0][nt], 0, 0, 0);
                    acc[1][nt] = __builtin_amdgcn_mfma_f32_16x16x32_bf16(a1, bv, acc[1][nt], 0, 0, 0);
                }
            }
        }
    }

    __syncthreads();

    // epilogue: out[b][c][t0+row] = O/l + x ; frag reg r is contiguous in t
    {
        float linv[2][4];
        #pragma unroll
        for (int m = 0; m < 2; ++m)
            #pragma unroll
            for (int r = 0; r < 4; ++r)
                linv[m][r] = 1.f / Lrun[m * 16 + quad * 4 + r];

        #pragma unroll
        for (int m = 0; m < 2; ++m)
            #pragma unroll
            for (int nt = 0; nt < 4; ++nt) {
                int c = w * 64 + nt * 16 + l15;
                size_t base = ((size_t)(b * CC + c)) * TT + t0 + m * 16 + quad * 4;
                float4 xr = *(const float4*)(x + base);
                float4 o;
                o.x = acc[m][nt][0] * linv[m][0] + xr.x;
                o.y = acc[m][nt][1] * linv[m][1] + xr.y;
                o.z = acc[m][nt][2] * linv[m][2] + xr.z;
                o.w = acc[m][nt][3] * linv[m][3] + xr.w;
                *(float4*)(out + base) = o;
            }
    }
}

// ---------------------------------------------------------------------------
extern "C" void kernel_launch(void* const* d_in, const int* in_sizes, int n_in,
                              void* d_out, int out_size, void* d_ws, size_t ws_size,
                              hipStream_t stream) {
    const float* x  = (const float*)d_in[0];
    const float* Wq = (const float*)d_in[1];
    const float* bq = (const float*)d_in[2];
    const float* Wk = (const float*)d_in[3];
    const float* bk = (const float*)d_in[4];
    const float* Wv = (const float*)d_in[5];
    const float* bv = (const float*)d_in[6];
    float* out = (float*)d_out;

    // workspace: Q,K bf16 [B][T][32] (1 MB each), V bf16 [B][C][T] (8 MB)
    bf16* Qw = (bf16*)d_ws;
    bf16* Kw = Qw + (size_t)BB * TT * CQ;
    bf16* Vw = Kw + (size_t)BB * TT * CQ;

    dim3 blk(256);
    proj_kernel<<<dim3(TT / 64, 1, BB), blk, 0, stream>>>(x, Wq, bq, Qw, CQ, 0);
    proj_kernel<<<dim3(TT / 64, 1, BB), blk, 0, stream>>>(x, Wk, bk, Kw, CQ, 0);
    proj_kernel<<<dim3(TT / 64, CC / 32, BB), blk, 0, stream>>>(x, Wv, bv, Vw, CC, 1);
    flash_kernel<<<dim3(TT / 32, BB), blk, 0, stream>>>(Qw, Kw, Vw, x, out);
}

// Round 3
// 260.063 us; speedup vs baseline: 28.5280x; 1.0501x over previous
//
#include <hip/hip_runtime.h>
#include <hip/hip_bf16.h>

// Problem constants (B=4, C=256, T=4096, Cq=32)
#define BB 4
#define CC 256
#define TT 4096
#define CQ 32

typedef __bf16 bf16;
typedef __bf16 bf16x8 __attribute__((ext_vector_type(8)));
typedef float floatx4 __attribute__((ext_vector_type(4)));

// ---------------------------------------------------------------------------
// Unified projection: one kernel for Q, K, V. fp32 compute, bf16 output.
// Grid (TT/64, 10, BB), block 256. blockIdx.y: 0=Q, 1=K, 2..9=V o-tile.
// Q,K -> [b][t][o] (o contiguous, 32). V -> [b][o][t] (t contiguous).
// 10 blocks per (t0,b) -> 10 blocks/CU for latency hiding.
// ---------------------------------------------------------------------------
__global__ __launch_bounds__(256) void proj_kernel(
    const float* __restrict__ x,
    const float* __restrict__ Wq, const float* __restrict__ bq,
    const float* __restrict__ Wk, const float* __restrict__ bk,
    const float* __restrict__ Wv, const float* __restrict__ bv,
    bf16* __restrict__ Qo, bf16* __restrict__ Ko, bf16* __restrict__ Vo)
{
    __shared__ float ws[32 * 256];   // [o_local][c]

    const int tid = threadIdx.x;
    const int t0  = blockIdx.x * 64;
    const int y   = blockIdx.y;
    const int b   = blockIdx.z;

    const float* W;  const float* bias;  int o0;
    if (y == 0)      { W = Wq; bias = bq; o0 = 0; }
    else if (y == 1) { W = Wk; bias = bk; o0 = 0; }
    else             { W = Wv; bias = bv; o0 = (y - 2) * 32; }

    #pragma unroll
    for (int it = 0; it < 8; ++it) {
        int idx = it * 256 + tid;
        int j   = idx >> 6;
        int c4  = idx & 63;
        float4 v = *(const float4*)(W + (size_t)(o0 + j) * CC + c4 * 4);
        *(float4*)(ws + j * 256 + c4 * 4) = v;
    }
    __syncthreads();

    const int t    = tid & 63;
    const int osub = tid >> 6;
    const float* xcol = x + (size_t)b * CC * TT + t0 + t;

    float acc[8];
    #pragma unroll
    for (int jj = 0; jj < 8; ++jj) acc[jj] = bias[o0 + osub * 8 + jj];

    for (int c = 0; c < 256; c += 4) {
        float x0 = xcol[(size_t)(c + 0) * TT];
        float x1 = xcol[(size_t)(c + 1) * TT];
        float x2 = xcol[(size_t)(c + 2) * TT];
        float x3 = xcol[(size_t)(c + 3) * TT];
        #pragma unroll
        for (int jj = 0; jj < 8; ++jj) {
            const float4 w4 = *(const float4*)(ws + (osub * 8 + jj) * 256 + c);
            acc[jj] += w4.x * x0 + w4.y * x1 + w4.z * x2 + w4.w * x3;
        }
    }

    if (y < 2) {
        bf16* outp = (y == 0 ? Qo : Ko);
        bf16x8 v;
        #pragma unroll
        for (int jj = 0; jj < 8; ++jj) v[jj] = (bf16)acc[jj];
        *(bf16x8*)(outp + ((size_t)(b * TT + t0 + t)) * CQ + osub * 8) = v;
    } else {
        #pragma unroll
        for (int jj = 0; jj < 8; ++jj)
            Vo[((size_t)(b * CC + o0 + osub * 8 + jj)) * TT + t0 + t] = (bf16)acc[jj];
    }
}

// ---------------------------------------------------------------------------
// Flash attention, bf16 MFMA, minimal LDS. Br=32, Bc=64, 4 waves.
// Grid (TT/32, BB). Q:[b][t][32], K:[b][s][32], V:[b][c][t] (all bf16).
// MFMA 16x16x32 layouts (verified m89/m120):
//   A[m=lane&15][k=quad*8+j], B[k=quad*8+j][n=lane&15],
//   C/D[row=quad*4+r][col=lane&15], quad=lane>>4.
// Q A-frags: registers (loop-invariant). K,V B-frags: direct global loads
// (16 contiguous bytes/lane in these layouts; V frag-loads consume whole
// 64B lines — no over-fetch). LDS only for the S->P softmax round-trip.
// 2 barriers per tile. V frags prefetched at loop top (cross both barriers).
// ---------------------------------------------------------------------------
__global__ __launch_bounds__(256) void flash_kernel(
    const bf16* __restrict__ Q, const bf16* __restrict__ K,
    const bf16* __restrict__ V, const float* __restrict__ x,
    float* __restrict__ out)
{
    __shared__ float Sf[32 * 68];     // [r][s] fp32 scores
    __shared__ bf16  Ps[32 * 72];     // [r][s] bf16 probabilities
    __shared__ float Mrun[32], alphaS[32], Lrun[32];

    const int tid  = threadIdx.x;
    const int t0   = blockIdx.x * 32;
    const int b    = blockIdx.y;
    const int lane = tid & 63;
    const int w    = tid >> 6;
    const int l15  = lane & 15;
    const int quad = lane >> 4;

    // loop-invariant Q A-frags (rows t0+l15, t0+16+l15)
    const bf16* Qb = Q + (size_t)(b * TT) * CQ;
    bf16x8 a0 = *(const bf16x8*)(Qb + (size_t)(t0 + l15) * CQ + quad * 8);
    bf16x8 a1 = *(const bf16x8*)(Qb + (size_t)(t0 + 16 + l15) * CQ + quad * 8);

    if (tid < 32) { Mrun[tid] = -1.0e30f; Lrun[tid] = 0.f; }

    floatx4 acc[2][4] = {};

    const bf16* Kb = K + (size_t)b * TT * CQ;
    const bf16* Vw = V + ((size_t)b * CC + w * 64) * TT;   // wave's 64 c-rows

    for (int st = 0; st < TT / 64; ++st) {
        const int s0 = st * 64;

        // K B-frag (cols s0 + w*16 + l15), direct from global
        bf16x8 bk = *(const bf16x8*)(Kb + (size_t)(s0 + w * 16 + l15) * CQ + quad * 8);

        // V B-frag prefetch: vf[kt][nt] = V[c = w*64+nt*16+l15][s0+kt*32+quad*8 ..+8]
        bf16x8 vf[2][4];
        #pragma unroll
        for (int nt = 0; nt < 4; ++nt) {
            const bf16* vp = Vw + (size_t)(nt * 16 + l15) * TT + s0 + quad * 8;
            vf[0][nt] = *(const bf16x8*)(vp);
            vf[1][nt] = *(const bf16x8*)(vp + 32);
        }

        // S = Q K^T (2 MFMAs/wave) and scatter to Sf
        {
            floatx4 sc0 = {}, sc1 = {};
            sc0 = __builtin_amdgcn_mfma_f32_16x16x32_bf16(a0, bk, sc0, 0, 0, 0);
            sc1 = __builtin_amdgcn_mfma_f32_16x16x32_bf16(a1, bk, sc1, 0, 0, 0);
            #pragma unroll
            for (int r = 0; r < 4; ++r) {
                Sf[(quad * 4 + r) * 68 + w * 16 + l15]      = sc0[r];
                Sf[(16 + quad * 4 + r) * 68 + w * 16 + l15] = sc1[r];
            }
        }
        __syncthreads();   // A: Sf complete

        // online softmax: row r = tid>>3 (8 threads/row), cols (tid&7)*8..+8
        {
            int r = tid >> 3, c8 = tid & 7;
            float* sp = Sf + r * 68 + c8 * 8;
            float4 f0 = *(const float4*)(sp);
            float4 f1 = *(const float4*)(sp + 4);
            float mold = Mrun[r];
            float mx = fmaxf(fmaxf(fmaxf(f0.x, f0.y), fmaxf(f0.z, f0.w)),
                             fmaxf(fmaxf(f1.x, f1.y), fmaxf(f1.z, f1.w)));
            mx = fmaxf(mx, __shfl_xor(mx, 1));
            mx = fmaxf(mx, __shfl_xor(mx, 2));
            mx = fmaxf(mx, __shfl_xor(mx, 4));
            float m_new = fmaxf(mold, mx);
            float p[8];
            p[0] = __expf(f0.x - m_new); p[1] = __expf(f0.y - m_new);
            p[2] = __expf(f0.z - m_new); p[3] = __expf(f0.w - m_new);
            p[4] = __expf(f1.x - m_new); p[5] = __expf(f1.y - m_new);
            p[6] = __expf(f1.z - m_new); p[7] = __expf(f1.w - m_new);
            float sum = (p[0]+p[1]+p[2]+p[3]) + (p[4]+p[5]+p[6]+p[7]);
            sum += __shfl_xor(sum, 1);
            sum += __shfl_xor(sum, 2);
            sum += __shfl_xor(sum, 4);
            bf16x8 pv;
            #pragma unroll
            for (int j = 0; j < 8; ++j) pv[j] = (bf16)p[j];
            *(bf16x8*)(Ps + r * 72 + c8 * 8) = pv;
            if (c8 == 0) {
                float al = __expf(mold - m_new);
                alphaS[r] = al;
                Mrun[r]   = m_new;
                Lrun[r]   = Lrun[r] * al + sum;
            }
        }
        __syncthreads();   // B: Ps + stats complete

        // O = O*alpha + P @ V_tile (16 MFMAs/wave)
        {
            float al[2][4];
            #pragma unroll
            for (int m = 0; m < 2; ++m)
                #pragma unroll
                for (int r = 0; r < 4; ++r)
                    al[m][r] = alphaS[m * 16 + quad * 4 + r];
            #pragma unroll
            for (int m = 0; m < 2; ++m)
                #pragma unroll
                for (int nt = 0; nt < 4; ++nt)
                    #pragma unroll
                    for (int r = 0; r < 4; ++r)
                        acc[m][nt][r] *= al[m][r];

            #pragma unroll
            for (int kt = 0; kt < 2; ++kt) {
                bf16x8 pa0 = *(const bf16x8*)(Ps + l15 * 72 + kt * 32 + quad * 8);
                bf16x8 pa1 = *(const bf16x8*)(Ps + (16 + l15) * 72 + kt * 32 + quad * 8);
                #pragma unroll
                for (int nt = 0; nt < 4; ++nt) {
                    acc[0][nt] = __builtin_amdgcn_mfma_f32_16x16x32_bf16(pa0, vf[kt][nt], acc[0][nt], 0, 0, 0);
                    acc[1][nt] = __builtin_amdgcn_mfma_f32_16x16x32_bf16(pa1, vf[kt][nt], acc[1][nt], 0, 0, 0);
                }
            }
        }
    }

    // epilogue: out[b][c][t0+row] = O/l + x ; frag reg r is contiguous in t
    {
        float linv[2][4];
        #pragma unroll
        for (int m = 0; m < 2; ++m)
            #pragma unroll
            for (int r = 0; r < 4; ++r)
                linv[m][r] = 1.f / Lrun[m * 16 + quad * 4 + r];

        #pragma unroll
        for (int m = 0; m < 2; ++m)
            #pragma unroll
            for (int nt = 0; nt < 4; ++nt) {
                int c = w * 64 + nt * 16 + l15;
                size_t base = ((size_t)(b * CC + c)) * TT + t0 + m * 16 + quad * 4;
                float4 xr = *(const float4*)(x + base);
                float4 o;
                o.x = acc[m][nt][0] * linv[m][0] + xr.x;
                o.y = acc[m][nt][1] * linv[m][1] + xr.y;
                o.z = acc[m][nt][2] * linv[m][2] + xr.z;
                o.w = acc[m][nt][3] * linv[m][3] + xr.w;
                *(float4*)(out + base) = o;
            }
    }
}

// ---------------------------------------------------------------------------
extern "C" void kernel_launch(void* const* d_in, const int* in_sizes, int n_in,
                              void* d_out, int out_size, void* d_ws, size_t ws_size,
                              hipStream_t stream) {
    const float* x  = (const float*)d_in[0];
    const float* Wq = (const float*)d_in[1];
    const float* bq = (const float*)d_in[2];
    const float* Wk = (const float*)d_in[3];
    const float* bk = (const float*)d_in[4];
    const float* Wv = (const float*)d_in[5];
    const float* bv = (const float*)d_in[6];
    float* out = (float*)d_out;

    bf16* Qw = (bf16*)d_ws;                         // [B][T][32]
    bf16* Kw = Qw + (size_t)BB * TT * CQ;           // [B][T][32]
    bf16* Vw = Kw + (size_t)BB * TT * CQ;           // [B][C][T]

    dim3 blk(256);
    proj_kernel<<<dim3(TT / 64, 10, BB), blk, 0, stream>>>(
        x, Wq, bq, Wk, bk, Wv, bv, Qw, Kw, Vw);
    flash_kernel<<<dim3(TT / 32, BB), blk, 0, stream>>>(Qw, Kw, Vw, x, out);
}

// Round 4
// 254.601 us; speedup vs baseline: 29.1401x; 1.0215x over previous
//
#include <hip/hip_runtime.h>
#include <hip/hip_bf16.h>

// Problem constants (B=4, C=256, T=4096, Cq=32)
#define BB 4
#define CC 256
#define TT 4096
#define CQ 32
#define LOG2E 1.44269504088896340736f

typedef __bf16 bf16;
typedef __bf16 bf16x4 __attribute__((ext_vector_type(4)));
typedef __bf16 bf16x8 __attribute__((ext_vector_type(8)));
typedef float floatx4 __attribute__((ext_vector_type(4)));

// ---------------------------------------------------------------------------
// Unified projection. Grid (TT/256, 10, BB), block 256. y: 0=Q,1=K,2..9=V.
// 4 t-cols per thread -> W-tile LDS reads amortized 4x (round-3 was
// LDS-read-bound re-reading W per t). Q is pre-scaled by log2(e) so the
// flash softmax runs in the exp2 domain (v_exp_f32 native).
// ---------------------------------------------------------------------------
__global__ __launch_bounds__(256) void proj_kernel(
    const float* __restrict__ x,
    const float* __restrict__ Wq, const float* __restrict__ bq,
    const float* __restrict__ Wk, const float* __restrict__ bk,
    const float* __restrict__ Wv, const float* __restrict__ bv,
    bf16* __restrict__ Qo, bf16* __restrict__ Ko, bf16* __restrict__ Vo)
{
    __shared__ float ws[32 * 256];   // [o_local][c]

    const int tid = threadIdx.x;
    const int t0  = blockIdx.x * 256;
    const int y   = blockIdx.y;
    const int b   = blockIdx.z;

    const float* W;  const float* bias;  int o0;
    if (y == 0)      { W = Wq; bias = bq; o0 = 0; }
    else if (y == 1) { W = Wk; bias = bk; o0 = 0; }
    else             { W = Wv; bias = bv; o0 = (y - 2) * 32; }

    #pragma unroll
    for (int it = 0; it < 8; ++it) {
        int idx = it * 256 + tid;
        int j = idx >> 6, c4 = idx & 63;
        *(float4*)(ws + j * 256 + c4 * 4) =
            *(const float4*)(W + (size_t)(o0 + j) * CC + c4 * 4);
    }
    __syncthreads();

    const int lane = tid & 63;
    const int osub = tid >> 6;
    const int t = t0 + lane * 4;
    const float* xp = x + (size_t)b * CC * TT + t;

    float acc[8][4];
    #pragma unroll
    for (int jj = 0; jj < 8; ++jj) {
        float bv_ = bias[o0 + osub * 8 + jj];
        acc[jj][0] = bv_; acc[jj][1] = bv_; acc[jj][2] = bv_; acc[jj][3] = bv_;
    }

    for (int c = 0; c < 256; c += 4) {
        float xv[4][4];
        #pragma unroll
        for (int cc = 0; cc < 4; ++cc)
            *(float4*)xv[cc] = *(const float4*)(xp + (size_t)(c + cc) * TT);
        #pragma unroll
        for (int jj = 0; jj < 8; ++jj) {
            float4 w4 = *(const float4*)(ws + (osub * 8 + jj) * 256 + c);
            #pragma unroll
            for (int tt = 0; tt < 4; ++tt)
                acc[jj][tt] += w4.x * xv[0][tt] + w4.y * xv[1][tt]
                             + w4.z * xv[2][tt] + w4.w * xv[3][tt];
        }
    }

    if (y < 2) {
        const float s = (y == 0) ? LOG2E : 1.0f;
        bf16* outp = (y == 0) ? Qo : Ko;
        #pragma unroll
        for (int tt = 0; tt < 4; ++tt) {
            bf16x8 v;
            #pragma unroll
            for (int jj = 0; jj < 8; ++jj) v[jj] = (bf16)(acc[jj][tt] * s);
            *(bf16x8*)(outp + ((size_t)(b * TT + t + tt)) * CQ + osub * 8) = v;
        }
    } else {
        #pragma unroll
        for (int jj = 0; jj < 8; ++jj) {
            bf16x4 v;
            #pragma unroll
            for (int tt = 0; tt < 4; ++tt) v[tt] = (bf16)acc[jj][tt];
            *(bf16x4*)(Vo + ((size_t)(b * CC + o0 + osub * 8 + jj)) * TT + t) = v;
        }
    }
}

// ---------------------------------------------------------------------------
// Flash attention, bf16 MFMA, ZERO in-loop barriers.
// Grid (TT/32, BB), 256 threads = 4 waves. Wave w: c-half cw=w&1 (128 cols),
// s-half sw=w>>1 (2048 s, 32 tiles of 64). Each wave computes its own S-tile
// (2x-redundant QK), in-register softmax (shfl_xor over 16 row-sharing
// lanes), wave-private LDS round-trip for the P C->A layout transform
// (lgkmcnt only). End: cross-wave (sw pair) m/l/O combine with 2 barriers.
// MFMA 16x16x32 layouts (verified m89/m120):
//   A[m=l15][k=quad*8+j], B[k=quad*8+j][n=l15], C/D[row=quad*4+r][col=l15].
// ---------------------------------------------------------------------------
__global__ __launch_bounds__(256, 2) void flash_kernel(
    const bf16* __restrict__ Q, const bf16* __restrict__ K,
    const bf16* __restrict__ V, const float* __restrict__ x,
    float* __restrict__ out)
{
    // union: Pbuf [4][32*72] bf16 (18432 B) reused as Obuf [2][32*132] f32 (33792 B)
    __shared__ __align__(16) char smem[33792];
    __shared__ float MB[4][32], LB[4][32];

    const int tid  = threadIdx.x;
    const int t0   = blockIdx.x * 32;
    const int b    = blockIdx.y;
    const int lane = tid & 63;
    const int w    = tid >> 6;
    const int l15  = lane & 15;
    const int quad = lane >> 4;
    const int cw   = w & 1;
    const int sw   = w >> 1;
    const int c0   = cw * 128;

    bf16* Pw = (bf16*)smem + w * (32 * 72);

    const bf16* Qb = Q + (size_t)b * TT * CQ;
    bf16x8 a0 = *(const bf16x8*)(Qb + (size_t)(t0 + l15) * CQ + quad * 8);
    bf16x8 a1 = *(const bf16x8*)(Qb + (size_t)(t0 + 16 + l15) * CQ + quad * 8);

    const bf16* Kb = K + (size_t)b * TT * CQ;
    const bf16* Vb = V + ((size_t)b * CC + c0) * TT;

    float mrun[2][4], lrun[2][4];
    #pragma unroll
    for (int m = 0; m < 2; ++m)
        #pragma unroll
        for (int r = 0; r < 4; ++r) { mrun[m][r] = -1.0e30f; lrun[m][r] = 0.f; }

    floatx4 acc[2][8] = {};

    for (int st = 0; st < 32; ++st) {
        const int s0 = sw * (TT / 2) + st * 64;

        // K B-frags (4) and V B-frags (16) direct from global, issued early
        bf16x8 bk[4];
        #pragma unroll
        for (int nt = 0; nt < 4; ++nt)
            bk[nt] = *(const bf16x8*)(Kb + (size_t)(s0 + nt * 16 + l15) * CQ + quad * 8);

        bf16x8 vf[2][8];
        #pragma unroll
        for (int ntc = 0; ntc < 8; ++ntc) {
            const bf16* vp = Vb + (size_t)(ntc * 16 + l15) * TT + s0 + quad * 8;
            vf[0][ntc] = *(const bf16x8*)vp;
            vf[1][ntc] = *(const bf16x8*)(vp + 32);
        }

        // S = Q K^T (8 MFMAs), scores already in log2 domain (Q pre-scaled)
        floatx4 sc[2][4] = {};
        #pragma unroll
        for (int nt = 0; nt < 4; ++nt) {
            sc[0][nt] = __builtin_amdgcn_mfma_f32_16x16x32_bf16(a0, bk[nt], sc[0][nt], 0, 0, 0);
            sc[1][nt] = __builtin_amdgcn_mfma_f32_16x16x32_bf16(a1, bk[nt], sc[1][nt], 0, 0, 0);
        }

        // in-register online softmax (row = m*16 + quad*4 + r)
        float al[2][4];
        #pragma unroll
        for (int m = 0; m < 2; ++m)
            #pragma unroll
            for (int r = 0; r < 4; ++r) {
                float mx = fmaxf(fmaxf(sc[m][0][r], sc[m][1][r]),
                                 fmaxf(sc[m][2][r], sc[m][3][r]));
                mx = fmaxf(mx, __shfl_xor(mx, 1));
                mx = fmaxf(mx, __shfl_xor(mx, 2));
                mx = fmaxf(mx, __shfl_xor(mx, 4));
                mx = fmaxf(mx, __shfl_xor(mx, 8));
                float mnew = fmaxf(mrun[m][r], mx);
                al[m][r] = exp2f(mrun[m][r] - mnew);
                mrun[m][r] = mnew;
            }

        float p[2][4][4];
        #pragma unroll
        for (int m = 0; m < 2; ++m)
            #pragma unroll
            for (int nt = 0; nt < 4; ++nt)
                #pragma unroll
                for (int r = 0; r < 4; ++r)
                    p[m][nt][r] = exp2f(sc[m][nt][r] - mrun[m][r]);

        #pragma unroll
        for (int m = 0; m < 2; ++m)
            #pragma unroll
            for (int r = 0; r < 4; ++r) {
                float s = (p[m][0][r] + p[m][1][r]) + (p[m][2][r] + p[m][3][r]);
                s += __shfl_xor(s, 1);
                s += __shfl_xor(s, 2);
                s += __shfl_xor(s, 4);
                s += __shfl_xor(s, 8);
                lrun[m][r] = lrun[m][r] * al[m][r] + s;
            }

        #pragma unroll
        for (int m = 0; m < 2; ++m)
            #pragma unroll
            for (int ntc = 0; ntc < 8; ++ntc)
                #pragma unroll
                for (int r = 0; r < 4; ++r)
                    acc[m][ntc][r] *= al[m][r];

        // P: C-layout regs -> wave-private LDS -> A-layout frags (no barrier)
        #pragma unroll
        for (int m = 0; m < 2; ++m)
            #pragma unroll
            for (int nt = 0; nt < 4; ++nt)
                #pragma unroll
                for (int r = 0; r < 4; ++r)
                    Pw[(m * 16 + quad * 4 + r) * 72 + nt * 16 + l15] = (bf16)p[m][nt][r];

        bf16x8 pa[2][2];
        #pragma unroll
        for (int m = 0; m < 2; ++m)
            #pragma unroll
            for (int kt = 0; kt < 2; ++kt)
                pa[m][kt] = *(const bf16x8*)(Pw + (m * 16 + l15) * 72 + kt * 32 + quad * 8);

        // O += P @ V (32 MFMAs)
        #pragma unroll
        for (int kt = 0; kt < 2; ++kt)
            #pragma unroll
            for (int ntc = 0; ntc < 8; ++ntc) {
                acc[0][ntc] = __builtin_amdgcn_mfma_f32_16x16x32_bf16(pa[0][kt], vf[kt][ntc], acc[0][ntc], 0, 0, 0);
                acc[1][ntc] = __builtin_amdgcn_mfma_f32_16x16x32_bf16(pa[1][kt], vf[kt][ntc], acc[1][ntc], 0, 0, 0);
            }
    }

    // ---- cross-wave combine (sw pairs share c-half), 2 barriers total ----
    if (l15 == 0) {
        #pragma unroll
        for (int m = 0; m < 2; ++m)
            #pragma unroll
            for (int r = 0; r < 4; ++r) {
                MB[w][m * 16 + quad * 4 + r] = mrun[m][r];
                LB[w][m * 16 + quad * 4 + r] = lrun[m][r];
            }
    }
    __syncthreads();

    const int pw = w ^ 2;
    float ascale[2][4], linv[2][4];
    #pragma unroll
    for (int m = 0; m < 2; ++m)
        #pragma unroll
        for (int r = 0; r < 4; ++r) {
            int row = m * 16 + quad * 4 + r;
            float mo = MB[pw][row], lo = LB[pw][row];
            float mf = fmaxf(mrun[m][r], mo);
            float as = exp2f(mrun[m][r] - mf);
            float lf = lrun[m][r] * as + lo * exp2f(mo - mf);
            ascale[m][r] = as;
            linv[m][r] = 1.f / lf;
        }

    float* Ob = (float*)smem + cw * (32 * 132);
    if (sw == 1) {
        #pragma unroll
        for (int m = 0; m < 2; ++m)
            #pragma unroll
            for (int ntc = 0; ntc < 8; ++ntc)
                #pragma unroll
                for (int r = 0; r < 4; ++r)
                    Ob[(m * 16 + quad * 4 + r) * 132 + ntc * 16 + l15] =
                        acc[m][ntc][r] * ascale[m][r];
    }
    __syncthreads();
    if (sw == 0) {
        #pragma unroll
        for (int m = 0; m < 2; ++m)
            #pragma unroll
            for (int ntc = 0; ntc < 8; ++ntc) {
                int c = c0 + ntc * 16 + l15;
                size_t base = ((size_t)(b * CC + c)) * TT + t0 + m * 16 + quad * 4;
                float4 xr = *(const float4*)(x + base);
                float4 o;
                o.x = (acc[m][ntc][0] * ascale[m][0] + Ob[(m * 16 + quad * 4 + 0) * 132 + ntc * 16 + l15]) * linv[m][0] + xr.x;
                o.y = (acc[m][ntc][1] * ascale[m][1] + Ob[(m * 16 + quad * 4 + 1) * 132 + ntc * 16 + l15]) * linv[m][1] + xr.y;
                o.z = (acc[m][ntc][2] * ascale[m][2] + Ob[(m * 16 + quad * 4 + 2) * 132 + ntc * 16 + l15]) * linv[m][2] + xr.z;
                o.w = (acc[m][ntc][3] * ascale[m][3] + Ob[(m * 16 + quad * 4 + 3) * 132 + ntc * 16 + l15]) * linv[m][3] + xr.w;
                *(float4*)(out + base) = o;
            }
    }
}

// ---------------------------------------------------------------------------
extern "C" void kernel_launch(void* const* d_in, const int* in_sizes, int n_in,
                              void* d_out, int out_size, void* d_ws, size_t ws_size,
                              hipStream_t stream) {
    const float* x  = (const float*)d_in[0];
    const float* Wq = (const float*)d_in[1];
    const float* bq = (const float*)d_in[2];
    const float* Wk = (const float*)d_in[3];
    const float* bk = (const float*)d_in[4];
    const float* Wv = (const float*)d_in[5];
    const float* bv = (const float*)d_in[6];
    float* out = (float*)d_out;

    bf16* Qw = (bf16*)d_ws;                         // [B][T][32] (pre-scaled by log2e)
    bf16* Kw = Qw + (size_t)BB * TT * CQ;           // [B][T][32]
    bf16* Vw = Kw + (size_t)BB * TT * CQ;           // [B][C][T]

    dim3 blk(256);
    proj_kernel<<<dim3(TT / 256, 10, BB), blk, 0, stream>>>(
        x, Wq, bq, Wk, bk, Wv, bv, Qw, Kw, Vw);
    flash_kernel<<<dim3(TT / 32, BB), blk, 0, stream>>>(Qw, Kw, Vw, x, out);
}